// Round 7
// baseline (43.022 us; speedup 1.0000x reference)
//
#include <hip/hip_runtime.h>

#define NB 32
#define NC 64
#define HW 25600            // 160*160
#define HW4 6400            // HW/4 (float4 per image)
#define CHUNK 64            // float4 per block (one wave, 1 each)
#define CHUNKS_PER_B 100    // HW4 / CHUNK
#define NBLOCKS1 3200       // NB * CHUNKS_PER_B  (12.5 waves/CU -> fine-grained balance)
#define NBLOCKS2 800        // NB*HW4/256 for the apply pass
#define BN_EPS 1e-5f
#define LEAKY 0.1f

typedef float vfloat4 __attribute__((ext_vector_type(4)));

// Pass 1: single-wave blocks. Each block computes 64 contiguous float4 mask
// elements (channel dot product), stores them (nontemporal), and writes one
// (sum, sumsq) pair. 3200 blocks -> 12/13 waves per CU (vs 12/16 with 800
// 4-wave blocks): smaller drain tail on the HBM sweep.
__global__ __launch_bounds__(64) void maskgen_pass1(
    const float* __restrict__ feats, const float* __restrict__ sf,
    float* __restrict__ mask, float* __restrict__ partials) {
    const int cid  = blockIdx.x;
    const int b    = cid / CHUNKS_PER_B;
    const int t    = (cid % CHUNKS_PER_B) * CHUNK + threadIdx.x;  // float4 idx in image
    const int lane = threadIdx.x;

    __shared__ float s_sf[NC];
    s_sf[lane] = sf[b * NC + lane];
    __syncthreads();

    const vfloat4* f4 = reinterpret_cast<const vfloat4*>(feats) + (size_t)b * NC * HW4 + t;
    vfloat4 acc0 = {0.f, 0.f, 0.f, 0.f};
    vfloat4 acc1 = {0.f, 0.f, 0.f, 0.f};
#pragma unroll 8
    for (int c = 0; c < NC; c += 2) {
        vfloat4 v0 = f4[(size_t)c * HW4];
        vfloat4 v1 = f4[(size_t)(c + 1) * HW4];
        float s0 = s_sf[c], s1 = s_sf[c + 1];
        acc0.x = fmaf(v0.x, s0, acc0.x); acc1.x = fmaf(v1.x, s1, acc1.x);
        acc0.y = fmaf(v0.y, s0, acc0.y); acc1.y = fmaf(v1.y, s1, acc1.y);
        acc0.z = fmaf(v0.z, s0, acc0.z); acc1.z = fmaf(v1.z, s1, acc1.z);
        acc0.w = fmaf(v0.w, s0, acc0.w); acc1.w = fmaf(v1.w, s1, acc1.w);
    }
    vfloat4 acc = acc0 + acc1;
    __builtin_nontemporal_store(acc, reinterpret_cast<vfloat4*>(mask) + (size_t)b * HW4 + t);

    float lsum = (acc.x + acc.y) + (acc.z + acc.w);
    float lsq  = acc.x * acc.x + acc.y * acc.y + acc.z * acc.z + acc.w * acc.w;
#pragma unroll
    for (int off = 32; off > 0; off >>= 1) {
        lsum += __shfl_down(lsum, off, 64);
        lsq  += __shfl_down(lsq,  off, 64);
    }
    if (lane == 0) {
        partials[cid]            = lsum;
        partials[NBLOCKS1 + cid] = lsq;
    }
}

// Pass 2 (fused stats + apply): every block redundantly reduces the 3200
// partials in fixed order (bitwise identical across blocks -> deterministic),
// then applies BN + LeakyReLU in-place (nontemporal both ways).
__global__ __launch_bounds__(256) void maskgen_pass2(
    float* __restrict__ mask, const float* __restrict__ partials,
    const float* __restrict__ bn_w, const float* __restrict__ bn_b) {
    double s = 0.0, q = 0.0;
    for (int i = threadIdx.x; i < NBLOCKS1; i += 256) {
        s += (double)partials[i];
        q += (double)partials[NBLOCKS1 + i];
    }
#pragma unroll
    for (int off = 32; off > 0; off >>= 1) {
        s += __shfl_down(s, off, 64);
        q += __shfl_down(q, off, 64);
    }
    __shared__ double sh[8];
    const int wave = threadIdx.x >> 6;
    if ((threadIdx.x & 63) == 0) { sh[wave] = s; sh[4 + wave] = q; }
    __syncthreads();

    const double S = (sh[0] + sh[1]) + (sh[2] + sh[3]);
    const double Q = (sh[4] + sh[5]) + (sh[6] + sh[7]);
    const double N = (double)NB * (double)HW;
    const double mean = S / N;
    const double var  = Q / N - mean * mean;
    const float inv   = rsqrtf((float)var + BN_EPS);
    const float scale = inv * bn_w[0];
    const float shift = bn_b[0] - (float)mean * scale;

    const int i = blockIdx.x * 256 + threadIdx.x;  // float4 idx, grid = NBLOCKS2
    vfloat4 v = __builtin_nontemporal_load(reinterpret_cast<vfloat4*>(mask) + i);
    vfloat4 r;
    r.x = fmaf(v.x, scale, shift); r.x = (r.x >= 0.f) ? r.x : LEAKY * r.x;
    r.y = fmaf(v.y, scale, shift); r.y = (r.y >= 0.f) ? r.y : LEAKY * r.y;
    r.z = fmaf(v.z, scale, shift); r.z = (r.z >= 0.f) ? r.z : LEAKY * r.z;
    r.w = fmaf(v.w, scale, shift); r.w = (r.w >= 0.f) ? r.w : LEAKY * r.w;
    __builtin_nontemporal_store(r, reinterpret_cast<vfloat4*>(mask) + i);
}

extern "C" void kernel_launch(void* const* d_in, const int* in_sizes, int n_in,
                              void* d_out, int out_size, void* d_ws, size_t ws_size,
                              hipStream_t stream) {
    const float* sf    = (const float*)d_in[0];   // [32,64,1,1]
    const float* feats = (const float*)d_in[1];   // [32,64,160,160]
    const float* bn_w  = (const float*)d_in[2];   // [1]
    const float* bn_b  = (const float*)d_in[3];   // [1]
    float* out      = (float*)d_out;              // [32,1,160,160] fp32
    float* partials = (float*)d_ws;               // 2*3200 floats

    maskgen_pass1<<<NBLOCKS1, 64, 0, stream>>>(feats, sf, out, partials);
    maskgen_pass2<<<NBLOCKS2, 256, 0, stream>>>(out, partials, bn_w, bn_b);
}

// Round 8
// 41.283 us; speedup vs baseline: 1.0421x; 1.0421x over previous
//
#include <hip/hip_runtime.h>

#define NB 32
#define NC 64
#define HW 25600          // 160*160
#define HW4 6400          // HW/4 (float4 per image)
#define BLKS_PER_B 25     // HW4 / 256
#define NBLOCKS 800       // NB * BLKS_PER_B
#define BN_EPS 1e-5f
#define LEAKY 0.1f

typedef float vfloat4 __attribute__((ext_vector_type(4)));

// Pass 1: channel dot product with a manual 8-deep double-buffered register
// pipeline: ~8-16 outstanding global loads per thread (vs ~4 at VGPR=32)
// to cover ~900-cycle HBM latency at 12 waves/CU residency.
// __launch_bounds__(256,2): VGPR cap 128 (expect ~90 used -> 16 waves/CU cap).
__global__ __launch_bounds__(256, 2) void maskgen_pass1(
    const float* __restrict__ feats, const float* __restrict__ sf,
    float* __restrict__ mask, float* __restrict__ partials) {
    const int b = blockIdx.x / BLKS_PER_B;
    const int t = (blockIdx.x % BLKS_PER_B) * 256 + threadIdx.x;  // float4 idx in image

    __shared__ float s_sf[NC];
    if (threadIdx.x < NC) s_sf[threadIdx.x] = sf[b * NC + threadIdx.x];
    __syncthreads();

    const vfloat4* f4 = reinterpret_cast<const vfloat4*>(feats) + (size_t)b * NC * HW4 + t;

    vfloat4 bufA[8], bufB[8];
    vfloat4 acc[4];
#pragma unroll
    for (int i = 0; i < 4; ++i) acc[i] = (vfloat4){0.f, 0.f, 0.f, 0.f};

#define LOADG(buf, g)                                                     \
    _Pragma("unroll") for (int i = 0; i < 8; ++i)                          \
        buf[i] = f4[(size_t)((g) * 8 + i) * HW4];

#define FMAG(buf, g)                                                      \
    _Pragma("unroll") for (int i = 0; i < 8; ++i) {                        \
        const float s = s_sf[(g) * 8 + i];                                 \
        acc[i & 3].x = fmaf(buf[i].x, s, acc[i & 3].x);                    \
        acc[i & 3].y = fmaf(buf[i].y, s, acc[i & 3].y);                    \
        acc[i & 3].z = fmaf(buf[i].z, s, acc[i & 3].z);                    \
        acc[i & 3].w = fmaf(buf[i].w, s, acc[i & 3].w);                    \
    }

    // software pipeline: one LOAD group in flight while the previous FMAs run
    LOADG(bufA, 0)
    LOADG(bufB, 1)
    FMAG(bufA, 0)
    LOADG(bufA, 2)
    FMAG(bufB, 1)
    LOADG(bufB, 3)
    FMAG(bufA, 2)
    LOADG(bufA, 4)
    FMAG(bufB, 3)
    LOADG(bufB, 5)
    FMAG(bufA, 4)
    LOADG(bufA, 6)
    FMAG(bufB, 5)
    LOADG(bufB, 7)
    FMAG(bufA, 6)
    FMAG(bufB, 7)
#undef LOADG
#undef FMAG

    vfloat4 a = (acc[0] + acc[1]) + (acc[2] + acc[3]);
    __builtin_nontemporal_store(a, reinterpret_cast<vfloat4*>(mask) + (size_t)b * HW4 + t);

    float lsum = (a.x + a.y) + (a.z + a.w);
    float lsq  = a.x * a.x + a.y * a.y + a.z * a.z + a.w * a.w;
#pragma unroll
    for (int off = 32; off > 0; off >>= 1) {
        lsum += __shfl_down(lsum, off, 64);
        lsq  += __shfl_down(lsq,  off, 64);
    }
    __shared__ float s_red[8];
    const int wave = threadIdx.x >> 6;
    if ((threadIdx.x & 63) == 0) { s_red[wave] = lsum; s_red[4 + wave] = lsq; }
    __syncthreads();
    if (threadIdx.x == 0) {
        partials[blockIdx.x]           = (s_red[0] + s_red[1]) + (s_red[2] + s_red[3]);
        partials[NBLOCKS + blockIdx.x] = (s_red[4] + s_red[5]) + (s_red[6] + s_red[7]);
    }
}

// Pass 2 (fused stats + apply): every block redundantly reduces the 800
// partials in fixed order (bitwise identical across blocks -> deterministic),
// then applies BN + LeakyReLU in-place (nontemporal both ways).
__global__ __launch_bounds__(256) void maskgen_pass2(
    float* __restrict__ mask, const float* __restrict__ partials,
    const float* __restrict__ bn_w, const float* __restrict__ bn_b) {
    double s = 0.0, q = 0.0;
    for (int i = threadIdx.x; i < NBLOCKS; i += 256) {
        s += (double)partials[i];
        q += (double)partials[NBLOCKS + i];
    }
#pragma unroll
    for (int off = 32; off > 0; off >>= 1) {
        s += __shfl_down(s, off, 64);
        q += __shfl_down(q, off, 64);
    }
    __shared__ double sh[8];
    const int wave = threadIdx.x >> 6;
    if ((threadIdx.x & 63) == 0) { sh[wave] = s; sh[4 + wave] = q; }
    __syncthreads();

    const double S = (sh[0] + sh[1]) + (sh[2] + sh[3]);
    const double Q = (sh[4] + sh[5]) + (sh[6] + sh[7]);
    const double N = (double)NB * (double)HW;
    const double mean = S / N;
    const double var  = Q / N - mean * mean;
    const float inv   = rsqrtf((float)var + BN_EPS);
    const float scale = inv * bn_w[0];
    const float shift = bn_b[0] - (float)mean * scale;

    const int i = blockIdx.x * 256 + threadIdx.x;  // float4 idx, grid = NB*HW4/256
    vfloat4 v = __builtin_nontemporal_load(reinterpret_cast<vfloat4*>(mask) + i);
    vfloat4 r;
    r.x = fmaf(v.x, scale, shift); r.x = (r.x >= 0.f) ? r.x : LEAKY * r.x;
    r.y = fmaf(v.y, scale, shift); r.y = (r.y >= 0.f) ? r.y : LEAKY * r.y;
    r.z = fmaf(v.z, scale, shift); r.z = (r.z >= 0.f) ? r.z : LEAKY * r.z;
    r.w = fmaf(v.w, scale, shift); r.w = (r.w >= 0.f) ? r.w : LEAKY * r.w;
    __builtin_nontemporal_store(r, reinterpret_cast<vfloat4*>(mask) + i);
}

extern "C" void kernel_launch(void* const* d_in, const int* in_sizes, int n_in,
                              void* d_out, int out_size, void* d_ws, size_t ws_size,
                              hipStream_t stream) {
    const float* sf    = (const float*)d_in[0];   // [32,64,1,1]
    const float* feats = (const float*)d_in[1];   // [32,64,160,160]
    const float* bn_w  = (const float*)d_in[2];   // [1]
    const float* bn_b  = (const float*)d_in[3];   // [1]
    float* out      = (float*)d_out;              // [32,1,160,160] fp32
    float* partials = (float*)d_ws;               // 2*800 floats

    maskgen_pass1<<<NBLOCKS, 256, 0, stream>>>(feats, sf, out, partials);
    maskgen_pass2<<<NBLOCKS, 256, 0, stream>>>(out, partials, bn_w, bn_b);
}